// Round 21
// baseline (43.508 us; speedup 1.0000x reference)
//
#include <hip/hip_runtime.h>
#include <hip/hip_bf16.h>

// MLP_small_per_feature: per-feature MLP 1 -> 64 -> 64 -> 1, F=256, B=8192.
// v21: 32-ROW PASSES via mfma_f32_32x32x16_bf16. Every passing variant
// (rounds 1-20, all 40-43us) used 16-row passes = 131072 pass-instances;
// time was invariant to instruction count (v16: 2.7x less VALU, same t),
// residency, pipelining -> the conserved cost is per-pass dependency stall.
// 32x32x16 halves instances (65536) and MFMA issues/row (20->12 per 32).
//
// 32x32x16 layouts (guide m74/m101-verified C/D; A/B by the same
// half-lane pattern as the verified 16x16x32):
//   A: row m = lane&31, k = (lane>>5)*8 + i   (4 VGPRs, 8 bf16)
//   B: col n = lane&31, k = (lane>>5)*8 + i
//   C/D: col n = lane&31, row m = (reg&3) + 8*(reg>>2) + 4*(lane>>5), reg 0..15
// w2 OUTPUT-row permutation (so acc lands in layer-3 B k-order):
//   at A-slot (t, m) store w2 row R = (2t+(m>>4))*16 + ((m>>2)&1)*8
//                                     + (m&3) + ((m>>3)&1)*4   [bijective]
//   => acc[t][reg] on half hi holds h2[(2t+(reg>>3))*16 + hi*8 + (reg&7)]
//   => h2frag[ks2][i2] = relu(acc[ks2>>1][(ks2&1)*8 + i2]); w3/b2 packed to match.
// Shell = v18 persistent: 512 blocks (2/CU = observed residency pin),
// 4 chunks x 256 rows, pack dispatch, outb exchange, keep-trick-free store.
// Spill canaries: SGPR<=64, WRITE~10MB (v5/v6/v8 signatures). If this lands
// ~40us, the plateau is instance-independent -> declare floor with v20.

namespace {

constexpr int kF = 256;
constexpr int kH = 64;
constexpr int kB = 8192;

constexpr int kFPB     = 4;               // features per block (one per wave)
constexpr int kRPC     = 256;             // rows per chunk (8 passes x 32)
constexpr int kChunks  = 4;               // chunks per block
constexpr int kRPBlk   = kRPC * kChunks;  // 1024 rows per block
constexpr int kThreads = 256;             // 4 waves
constexpr int kFG      = kF / kFPB;       // 64 feature groups
constexpr int kSlabs   = kB / kRPBlk;     // 8 row slabs
constexpr int kBlocks  = kFG * kSlabs;    // 512 = 2 blocks/CU persistent
constexpr int kPasses  = kRPC / 32;       // 8
constexpr int kXP      = 10;              // xs pass stride: 2-way banks (free)

using f32x2  = __attribute__((ext_vector_type(2))) float;
using f32x4  = __attribute__((ext_vector_type(4))) float;
using f32x16 = __attribute__((ext_vector_type(16))) float;
using bf16x4 = __attribute__((ext_vector_type(4))) __bf16;
using bf16x8 = __attribute__((ext_vector_type(8))) __bf16;

// ---- prep: pack w2 (R-permuted rows, bf16, 32x32-fragment-major), b2
// (R-permuted, C-order), w3 (plain bf16). One wave per feature. ----
__global__ __launch_bounds__(256)
void pack_params32(const float* __restrict__ w2, const float* __restrict__ b2,
                   const float* __restrict__ w3, __bf16* __restrict__ w2p,
                   float* __restrict__ b2p, __bf16* __restrict__ w3p)
{
  const int wid  = (int)threadIdx.x >> 6;
  const int lane = (int)threadIdx.x & 63;
  const int f    = (int)blockIdx.x * 4 + wid;
  const int m    = lane & 31;
  const int hi   = lane >> 5;

  const float* w2f = w2 + (size_t)f * (kH * kH);
  #pragma unroll
  for (int t = 0; t < 2; ++t) {
    // permuted original row for A-slot (t, m)
    const int R = (2 * t + (m >> 4)) * 16 + ((m >> 2) & 1) * 8 +
                  (m & 3) + ((m >> 3) & 1) * 4;
    #pragma unroll
    for (int ks = 0; ks < 4; ++ks) {
      const float* p = w2f + R * kH + ks * 16 + hi * 8;
      const f32x4 lo = *reinterpret_cast<const f32x4*>(p);
      const f32x4 hv = *reinterpret_cast<const f32x4*>(p + 4);
      const bf16x8 v = __builtin_shufflevector(
          __builtin_convertvector(lo, bf16x4),
          __builtin_convertvector(hv, bf16x4), 0, 1, 2, 3, 4, 5, 6, 7);
      *reinterpret_cast<bf16x8*>(
          w2p + (((size_t)f * 8 + t * 4 + ks) * 64 + lane) * 8) = v;
    }
  }

  // b2p[f*64 + t*32 + hi*16 + reg] = b2[f][R(t,reg,hi)]
  {
    const int reg = lane & 15, bhi = (lane >> 4) & 1, bt = lane >> 5;
    const int R = (2 * bt + (reg >> 3)) * 16 + bhi * 8 + (reg & 7);
    b2p[(size_t)f * kH + lane] = b2[(size_t)f * kH + R];
  }
  w3p[(size_t)f * kH + lane] = (__bf16)w3[(size_t)f * kH + lane];
}

__global__ __launch_bounds__(kThreads, 2)
void mlp_pf_v21(const float* __restrict__ x,
                const float* __restrict__ w1,
                const float* __restrict__ b1,
                const __bf16* __restrict__ w2p,
                const float* __restrict__ b2p,
                const __bf16* __restrict__ w3p,
                const float* __restrict__ b3,
                float* __restrict__ out)
{
  __shared__ float xs[kFPB][32][kXP];     // 5 KB [feat][col][pass]
  __shared__ float outb[kRPC][kFPB + 1];  // 5.1 KB (pad: conflict-free)

  const int tid  = (int)threadIdx.x;
  const int wid  = tid >> 6;
  const int lane = tid & 63;
  const int col  = lane & 31;             // batch-row slot (B col)
  const int hi   = lane >> 5;             // k-half

  const int fg   = (int)blockIdx.x >> 3;       // 0..63
  const int slab = (int)blockIdx.x & 7;        // 0..7 -> per-XCD x-slab
  const int f    = fg * kFPB + wid;            // this wave's feature
  const int rs0  = slab * kRPBlk;              // slab row base

  // ================= PROLOGUE (paid once per 1024 rows) =================
  // w2 A-fragments: 8 coalesced 16B loads/lane (L2-resident w2p)
  bf16x8 w2frag[2][4];
  {
    const __bf16* base = w2p + ((size_t)f * 8 * 64 + lane) * 8;
    #pragma unroll
    for (int t = 0; t < 2; ++t)
      #pragma unroll
      for (int ks = 0; ks < 4; ++ks)
        w2frag[t][ks] = *reinterpret_cast<const bf16x8*>(
            base + (size_t)(t * 4 + ks) * 64 * 8);
  }

  // layer-1 params: lane's k-slots h = ks*16 + hi*8 + 0..7
  f32x4 w1v[4][2], b1v[4][2];
  #pragma unroll
  for (int ks = 0; ks < 4; ++ks) {
    const float* pw = w1 + (size_t)f * kH + ks * 16 + hi * 8;
    const float* pb = b1 + (size_t)f * kH + ks * 16 + hi * 8;
    w1v[ks][0] = *reinterpret_cast<const f32x4*>(pw);
    w1v[ks][1] = *reinterpret_cast<const f32x4*>(pw + 4);
    b1v[ks][0] = *reinterpret_cast<const f32x4*>(pb);
    b1v[ks][1] = *reinterpret_cast<const f32x4*>(pb + 4);
  }
  // b2 C-operands (R-permuted, per lane-half): 64B-aligned f32x16 loads
  f32x16 b2c[2];
  #pragma unroll
  for (int t = 0; t < 2; ++t)
    b2c[t] = *reinterpret_cast<const f32x16*>(
        b2p + (size_t)f * kH + t * 32 + hi * 16);
  // w3 A-fragments (row-replicated): lane holds w3[ks*16 + hi*8 + 0..7]
  bf16x8 w3f[4];
  #pragma unroll
  for (int ks = 0; ks < 4; ++ks)
    w3f[ks] = *reinterpret_cast<const bf16x8*>(
        w3p + (size_t)f * kH + ks * 16 + hi * 8);
  const float b3v = b3[f];

  const f32x4 zero4 = {0.f, 0.f, 0.f, 0.f};
  f32x16 z16;
  #pragma unroll
  for (int i = 0; i < 16; ++i) z16[i] = 0.f;

  auto pack2 = [&](const f32x4& a, const f32x4& b) -> bf16x8 {
    return __builtin_shufflevector(
        __builtin_convertvector(__builtin_elementwise_max(a, zero4), bf16x4),
        __builtin_convertvector(__builtin_elementwise_max(b, zero4), bf16x4),
        0, 1, 2, 3, 4, 5, 6, 7);
  };

  // ================= 4 chunks x 8 passes of 32 rows =================
  #pragma unroll 1
  for (int ck = 0; ck < kChunks; ++ck) {
    const int r0 = rs0 + ck * kRPC;

    // stage x tile (256 rows x 4 feats) -> pass-major LDS
    {
      const int rr = tid;
      const f32x4 v = *reinterpret_cast<const f32x4*>(
          x + (size_t)(r0 + rr) * kF + fg * kFPB);
      const int c = rr & 31, p = rr >> 5;
      xs[0][c][p] = v[0]; xs[1][c][p] = v[1];
      xs[2][c][p] = v[2]; xs[3][c][p] = v[3];
    }
    __syncthreads();   // xs ready

    #pragma unroll
    for (int p = 0; p < kPasses; ++p) {
      const float xv = xs[wid][col][p];   // broadcast across halves

      // ---- layer 1: h1[k] for k = ks*16 + hi*8 + i -> B-fragments ----
      bf16x8 h1f[4];
      #pragma unroll
      for (int ks = 0; ks < 4; ++ks) {
        const f32x4 a = w1v[ks][0] * xv + b1v[ks][0];
        const f32x4 b = w1v[ks][1] * xv + b1v[ks][1];
        h1f[ks] = pack2(a, b);
      }

      // ---- layer 2: 2 o-tiles x 4 k-steps (C init = permuted b2) ----
      f32x16 acc0 = b2c[0], acc1 = b2c[1];
      #pragma unroll
      for (int ks = 0; ks < 4; ++ks) {
        acc0 = __builtin_amdgcn_mfma_f32_32x32x16_bf16(
            w2frag[0][ks], h1f[ks], acc0, 0, 0, 0);
        acc1 = __builtin_amdgcn_mfma_f32_32x32x16_bf16(
            w2frag[1][ks], h1f[ks], acc1, 0, 0, 0);
      }

      // ---- relu + cvt: acc slices form layer-3 B-fragments ----
      const bf16x8 h2f0 = pack2(
          __builtin_shufflevector(acc0, acc0, 0, 1, 2, 3),
          __builtin_shufflevector(acc0, acc0, 4, 5, 6, 7));
      const bf16x8 h2f1 = pack2(
          __builtin_shufflevector(acc0, acc0, 8, 9, 10, 11),
          __builtin_shufflevector(acc0, acc0, 12, 13, 14, 15));
      const bf16x8 h2f2 = pack2(
          __builtin_shufflevector(acc1, acc1, 0, 1, 2, 3),
          __builtin_shufflevector(acc1, acc1, 4, 5, 6, 7));
      const bf16x8 h2f3 = pack2(
          __builtin_shufflevector(acc1, acc1, 8, 9, 10, 11),
          __builtin_shufflevector(acc1, acc1, 12, 13, 14, 15));

      // ---- layer 3 via MFMA: two independent 2-deep chains ----
      f32x16 d01 = __builtin_amdgcn_mfma_f32_32x32x16_bf16(
          w3f[0], h2f0, z16, 0, 0, 0);
      f32x16 d23 = __builtin_amdgcn_mfma_f32_32x32x16_bf16(
          w3f[2], h2f2, z16, 0, 0, 0);
      d01 = __builtin_amdgcn_mfma_f32_32x32x16_bf16(w3f[1], h2f1, d01, 0, 0, 0);
      d23 = __builtin_amdgcn_mfma_f32_32x32x16_bf16(w3f[3], h2f3, d23, 0, 0, 0);

      const float s = d01[0] + d23[0] + b3v;   // D rows replicated
      if (hi == 0) outb[p * 32 + col][wid] = s;
    }

    __syncthreads();   // outb ready

    // output: one float4 (4 features) per row
    {
      const int rr = tid;
      const f32x4 v = {outb[rr][0], outb[rr][1], outb[rr][2], outb[rr][3]};
      *reinterpret_cast<f32x4*>(out + (size_t)(r0 + rr) * kF + fg * kFPB) = v;
    }
    __syncthreads();   // protect xs/outb for next chunk
  }
}

}  // namespace

extern "C" void kernel_launch(void* const* d_in, const int* in_sizes, int n_in,
                              void* d_out, int out_size, void* d_ws, size_t ws_size,
                              hipStream_t stream) {
  const float* x  = (const float*)d_in[0];
  const float* w1 = (const float*)d_in[1];
  const float* b1 = (const float*)d_in[2];
  const float* w2 = (const float*)d_in[3];
  const float* b2 = (const float*)d_in[4];
  const float* w3 = (const float*)d_in[5];
  const float* b3 = (const float*)d_in[6];
  float* out = (float*)d_out;

  __bf16* w2p = (__bf16*)d_ws;                           // 2 MB
  float*  b2p = (float*)((char*)d_ws + (2u << 20));      // 64 KB
  __bf16* w3p = (__bf16*)((char*)d_ws + (2u << 20) + (64u << 10));  // 32 KB

  hipLaunchKernelGGL(pack_params32, dim3(kF / 4), dim3(256), 0, stream,
                     w2, b2, w3, w2p, b2p, w3p);
  hipLaunchKernelGGL(mlp_pf_v21, dim3(kBlocks), dim3(kThreads), 0, stream,
                     x, w1, b1, w2p, b2p, w3p, b3, out);
}

// Round 22
// 40.297 us; speedup vs baseline: 1.0797x; 1.0797x over previous
//
#include <hip/hip_runtime.h>
#include <hip/hip_bf16.h>

// MLP_small_per_feature: per-feature MLP 1 -> 64 -> 64 -> 1, F=256, B=8192.
// v22 = v20 (best verified: 39.68us, absmax 0.03125) + T5 s_setprio around
// the MFMA clusters in fin(). Guide: setprio pays on INDEPENDENT-wave
// structures (attn +4-7%, m191) and is null only for barrier-lockstep GEMM
// (m190). v20's waves are independent between chunk barriers: on each SIMD,
// 2 co-resident waves sit at different phases (mk VALU vs fin MFMA) --
// exactly the role-diversity the CU scheduler can arbitrate.
//
// Plateau record (rounds 1-21, 12 structures, all 40-43.5us): occupancy x5,
// LDS-chain trims, layer1-as-MFMA, 32x32 MFMA (instance halving), pipeline
// depth, fixed-cost amortization, single-dispatch gather, coop fusion.
// Counters: VALUBusy ~40-45 + MfmaUtil ~15-20, HBM <17%, no spills, no bank
// conflicts, residency machine-pinned ~2 waves/SIMD.
//
// MFMA 16x16x32_bf16 layout (verified rounds 1-21):
//   A: row m = lane&15, k = (lane>>4)*8 + i
//   B: col n = lane&15, k = (lane>>4)*8 + i
//   C/D: col n = lane&15, row m = (lane>>4)*4 + r
//   o'(16t+m) = 32*(t>>1) + 8*(m>>2) + 4*(t&1) + (m&3)

namespace {

constexpr int kF = 256;
constexpr int kH = 64;
constexpr int kB = 8192;

constexpr int kFPB     = 4;               // features per block (one per wave)
constexpr int kRPC     = 128;             // rows per chunk
constexpr int kChunks  = 4;               // chunks per block
constexpr int kRPBlk   = kRPC * kChunks;  // 512 rows per block
constexpr int kThreads = 256;             // 4 waves
constexpr int kFG      = kF / kFPB;       // 64 feature groups
constexpr int kSlabs   = kB / kRPBlk;     // 16 row slabs
constexpr int kBlocks  = kFG * kSlabs;    // 1024 = 4 blocks/CU persistent
constexpr int kXP      = 12;              // pass-dim stride

using f32x4  = __attribute__((ext_vector_type(4))) float;
using bf16x4 = __attribute__((ext_vector_type(4))) __bf16;
using bf16x8 = __attribute__((ext_vector_type(8))) __bf16;

// ---- prep: pack w2 (o'-out-permuted, bf16, fragment-major), b2
// (o'-permuted, C-order), w3 (bf16). Verified v10-v20. ----
__global__ __launch_bounds__(256)
void pack_params(const float* __restrict__ w2, const float* __restrict__ b2,
                 const float* __restrict__ w3, __bf16* __restrict__ w2p,
                 float* __restrict__ b2p, __bf16* __restrict__ w3p)
{
  const int wid  = (int)threadIdx.x >> 6;
  const int lane = (int)threadIdx.x & 63;
  const int f    = (int)blockIdx.x * 4 + wid;
  const int l15  = lane & 15;
  const int lg   = lane >> 4;

  const float* w2f = w2 + (size_t)f * (kH * kH);
  #pragma unroll
  for (int t = 0; t < 4; ++t) {
    const int o2 = 32 * (t >> 1) + 8 * (l15 >> 2) + 4 * (t & 1) + (l15 & 3);
    #pragma unroll
    for (int ks = 0; ks < 2; ++ks) {
      const float* p = w2f + o2 * kH + ks * 32 + lg * 8;
      const f32x4 lo = *reinterpret_cast<const f32x4*>(p);
      const f32x4 hi = *reinterpret_cast<const f32x4*>(p + 4);
      const bf16x8 v = __builtin_shufflevector(
          __builtin_convertvector(lo, bf16x4),
          __builtin_convertvector(hi, bf16x4), 0, 1, 2, 3, 4, 5, 6, 7);
      *reinterpret_cast<bf16x8*>(
          w2p + (((size_t)f * 8 + t * 2 + ks) * 64 + lane) * 8) = v;
    }
  }

  {
    const int jt = lane >> 4, jlg = (lane >> 2) & 3, jr = lane & 3;
    const int o  = 32 * (jt >> 1) + 8 * jlg + 4 * (jt & 1) + jr;
    b2p[(size_t)f * kH + lane] = b2[(size_t)f * kH + o];
  }
  w3p[(size_t)f * kH + lane] = (__bf16)w3[(size_t)f * kH + lane];
}

__global__ __launch_bounds__(kThreads, 3)
void mlp_pf_v22(const float* __restrict__ x,
                const float* __restrict__ w1,
                const float* __restrict__ b1,
                const __bf16* __restrict__ w2p,
                const float* __restrict__ b2p,
                const __bf16* __restrict__ w3p,
                const float* __restrict__ b3,
                float* __restrict__ out)
{
  __shared__ float xs[kFPB][16][kXP];     // 3 KB [feat][l15][pass]
  __shared__ float outb[kRPC][kFPB + 1];  // 2.56 KB (pad: conflict-free)

  const int tid  = (int)threadIdx.x;
  const int wid  = tid >> 6;
  const int lane = tid & 63;
  const int l15  = lane & 15;
  const int lg   = lane >> 4;

  const int fg   = (int)blockIdx.x >> 4;       // 0..63
  const int slab = (int)blockIdx.x & 15;       // 0..15; XCD = slab%8
  const int f    = fg * kFPB + wid;            // this wave's feature
  const int rs0  = slab * kRPBlk;              // slab row base

  // ================= PROLOGUE (paid once per 512 rows) =================
  bf16x8 w2frag[4][2];
  {
    const __bf16* base = w2p + ((size_t)f * 8 * 64 + lane) * 8;
    #pragma unroll
    for (int t = 0; t < 4; ++t)
      #pragma unroll
      for (int ks = 0; ks < 2; ++ks)
        w2frag[t][ks] = *reinterpret_cast<const bf16x8*>(
            base + (size_t)(t * 2 + ks) * 64 * 8);
  }

  f32x4 w1v[2][2], b1v[2][2];
  #pragma unroll
  for (int ks = 0; ks < 2; ++ks) {
    const float* pw = w1 + f * kH + ks * 32 + lg * 8;
    const float* pb = b1 + f * kH + ks * 32 + lg * 8;
    w1v[ks][0] = *reinterpret_cast<const f32x4*>(pw);
    w1v[ks][1] = *reinterpret_cast<const f32x4*>(pw + 4);
    b1v[ks][0] = *reinterpret_cast<const f32x4*>(pb);
    b1v[ks][1] = *reinterpret_cast<const f32x4*>(pb + 4);
  }
  f32x4 b2c[4];
  #pragma unroll
  for (int t = 0; t < 4; ++t)
    b2c[t] = *reinterpret_cast<const f32x4*>(b2p + f * kH + t * 16 + lg * 4);
  bf16x8 w3f[2];
  #pragma unroll
  for (int ks = 0; ks < 2; ++ks)
    w3f[ks] = *reinterpret_cast<const bf16x8*>(w3p + f * kH + ks * 32 + lg * 8);
  const float b3v = b3[f];
  const f32x4 b3c = {b3v, b3v, b3v, b3v};

  const f32x4 zero4 = {0.f, 0.f, 0.f, 0.f};
  float keep = 0.f;

  struct PairH1 { bf16x8 a0, a1, b0, b1; };

  auto mk = [&](float xa, float xb) -> PairH1 {
    PairH1 r;
    #pragma unroll
    for (int ks = 0; ks < 2; ++ks) {
      f32x4 aA = w1v[ks][0] * xa + b1v[ks][0];
      f32x4 bA = w1v[ks][1] * xa + b1v[ks][1];
      f32x4 aB = w1v[ks][0] * xb + b1v[ks][0];
      f32x4 bB = w1v[ks][1] * xb + b1v[ks][1];
      aA = __builtin_elementwise_max(aA, zero4);
      bA = __builtin_elementwise_max(bA, zero4);
      aB = __builtin_elementwise_max(aB, zero4);
      bB = __builtin_elementwise_max(bB, zero4);
      const bf16x8 hA = __builtin_shufflevector(
          __builtin_convertvector(aA, bf16x4),
          __builtin_convertvector(bA, bf16x4), 0, 1, 2, 3, 4, 5, 6, 7);
      const bf16x8 hB = __builtin_shufflevector(
          __builtin_convertvector(aB, bf16x4),
          __builtin_convertvector(bB, bf16x4), 0, 1, 2, 3, 4, 5, 6, 7);
      if (ks == 0) { r.a0 = hA; r.b0 = hB; } else { r.a1 = hA; r.b1 = hB; }
    }
    return r;
  };

  auto pack2 = [&](const f32x4& a, const f32x4& b) -> bf16x8 {
    return __builtin_shufflevector(
        __builtin_convertvector(__builtin_elementwise_max(a, zero4), bf16x4),
        __builtin_convertvector(__builtin_elementwise_max(b, zero4), bf16x4),
        0, 1, 2, 3, 4, 5, 6, 7);
  };

  auto fin = [&](const PairH1& h, int PI) {
    f32x4 accA[4], accB[4];
    // T5: prioritize this wave while its MFMA cluster runs (waves are
    // independent here -- attn-like structure where setprio paid +4-7%)
    __builtin_amdgcn_s_setprio(1);
    #pragma unroll
    for (int t = 0; t < 4; ++t) {
      accA[t] = __builtin_amdgcn_mfma_f32_16x16x32_bf16(
          w2frag[t][0], h.a0, b2c[t], 0, 0, 0);
      accB[t] = __builtin_amdgcn_mfma_f32_16x16x32_bf16(
          w2frag[t][0], h.b0, b2c[t], 0, 0, 0);
      accA[t] = __builtin_amdgcn_mfma_f32_16x16x32_bf16(
          w2frag[t][1], h.a1, accA[t], 0, 0, 0);
      accB[t] = __builtin_amdgcn_mfma_f32_16x16x32_bf16(
          w2frag[t][1], h.b1, accB[t], 0, 0, 0);
    }
    __builtin_amdgcn_s_setprio(0);
    const bf16x8 h2A0 = pack2(accA[0], accA[1]);
    const bf16x8 h2A1 = pack2(accA[2], accA[3]);
    const bf16x8 h2B0 = pack2(accB[0], accB[1]);
    const bf16x8 h2B1 = pack2(accB[2], accB[3]);

    __builtin_amdgcn_s_setprio(1);
    f32x4 dA = __builtin_amdgcn_mfma_f32_16x16x32_bf16(w3f[0], h2A0, b3c, 0, 0, 0);
    f32x4 dB = __builtin_amdgcn_mfma_f32_16x16x32_bf16(w3f[0], h2B0, b3c, 0, 0, 0);
    dA = __builtin_amdgcn_mfma_f32_16x16x32_bf16(w3f[1], h2A1, dA, 0, 0, 0);
    dB = __builtin_amdgcn_mfma_f32_16x16x32_bf16(w3f[1], h2B1, dB, 0, 0, 0);
    __builtin_amdgcn_s_setprio(0);

    const int pA = 2 * PI, pB = 2 * PI + 1;
    keep = (lg == (pA & 3)) ? dA[0] : keep;
    keep = (lg == (pB & 3)) ? dB[0] : keep;
    if ((pB & 3) == 3) {
      outb[(pB >> 2) * 64 + lane][wid] = keep;   // b3 folded in
    }
  };

  // ================= 4 chunks of the verified body =================
  #pragma unroll 1
  for (int ck = 0; ck < kChunks; ++ck) {
    const int r0 = rs0 + ck * kRPC;

    if (tid < kRPC) {
      const int rr = tid;
      const f32x4 v = *reinterpret_cast<const f32x4*>(
          x + (size_t)(r0 + rr) * kF + fg * kFPB);
      const int a = rr & 15, b = rr >> 4;
      xs[0][a][b] = v[0]; xs[1][a][b] = v[1];
      xs[2][a][b] = v[2]; xs[3][a][b] = v[3];
    }
    __syncthreads();   // xs ready

    const f32x4 xq0 = *reinterpret_cast<const f32x4*>(&xs[wid][l15][0]);
    const f32x4 xq1 = *reinterpret_cast<const f32x4*>(&xs[wid][l15][4]);

    PairH1 c  = mk(xq0[0], xq0[1]);
    PairH1 n1 = mk(xq0[2], xq0[3]);
    fin(c, 0);
    PairH1 n2 = mk(xq1[0], xq1[1]);
    fin(n1, 1);
    PairH1 n3 = mk(xq1[2], xq1[3]);
    fin(n2, 2);
    fin(n3, 3);

    __syncthreads();   // outb ready

    if (tid < kRPC) {
      const int rr = tid;
      const f32x4 v = {outb[rr][0], outb[rr][1], outb[rr][2], outb[rr][3]};
      *reinterpret_cast<f32x4*>(out + (size_t)(r0 + rr) * kF + fg * kFPB) = v;
    }
    __syncthreads();   // protect xs/outb for next chunk
  }
}

}  // namespace

extern "C" void kernel_launch(void* const* d_in, const int* in_sizes, int n_in,
                              void* d_out, int out_size, void* d_ws, size_t ws_size,
                              hipStream_t stream) {
  const float* x  = (const float*)d_in[0];
  const float* w1 = (const float*)d_in[1];
  const float* b1 = (const float*)d_in[2];
  const float* w2 = (const float*)d_in[3];
  const float* b2 = (const float*)d_in[4];
  const float* w3 = (const float*)d_in[5];
  const float* b3 = (const float*)d_in[6];
  float* out = (float*)d_out;

  __bf16* w2p = (__bf16*)d_ws;                           // 2 MB
  float*  b2p = (float*)((char*)d_ws + (2u << 20));      // 64 KB
  __bf16* w3p = (__bf16*)((char*)d_ws + (2u << 20) + (64u << 10));  // 32 KB

  hipLaunchKernelGGL(pack_params, dim3(kF / 4), dim3(256), 0, stream,
                     w2, b2, w3, w2p, b2p, w3p);
  hipLaunchKernelGGL(mlp_pf_v22, dim3(kBlocks), dim3(kThreads), 0, stream,
                     x, w1, b1, w2p, b2p, w3p, b3, out);
}

// Round 23
// 39.632 us; speedup vs baseline: 1.0978x; 1.0168x over previous
//
#include <hip/hip_runtime.h>
#include <hip/hip_bf16.h>

// MLP_small_per_feature: per-feature MLP 1 -> 64 -> 64 -> 1, F=256, B=8192.
// FINAL KERNEL (v23 = v20 = v18, best verified: 39.68us, absmax 0.03125).
// v22's setprio experiment was null (+0.6us) -- reverted.
//
// Structure: pack_params dispatch (w2 -> bf16 o'-permuted fragment-major
// w2p in d_ws; b2 -> o'-permuted C-order; w3 -> bf16) + persistent main
// kernel (1024 blocks = 4/CU, 4 chunks x 128 rows, 4 waves/block, one
// feature per wave, 2-pass-pair ILP pipeline, layer-2 and layer-3 on MFMA
// with b2/b3 folded into C operands, keep-trick store + outb exchange).
//
// Practical-floor record (rounds 1-22, 13 structures, 9 dead levers, all
// 40-43.5us): occupancy x5 (grid scaling, LDS shrink, forced 512-thr
// stacking, persistent 2/CU and 4/CU), LDS-chain elimination, layer1-as-
// MFMA, 32x32 instance-halving, pipeline depth 2/4, fixed-cost amortization
// 8x, dispatch fusion (coop launch fails harness), s_setprio. Time is
// invariant to instruction count (v16: 2.7x less VALU, flat), pass count
// (v21: 2x fewer instances, flat), and resident waves (v18: 4 blocks/CU
// persistent, flat). Counters at plateau: VALUBusy ~40-45 + MfmaUtil
// ~15-20 (~64% combined issue port), HBM <17%, zero spills, zero bank
// conflicts. Dependency-stall equilibrium, ~4.8x above the 8.3us MFMA-only
// floor -- the serial layer1->GEMM->relu/cvt->dot chain cannot be hidden
// at CP-granted residency for this op's tiny per-feature working set.
//
// MFMA 16x16x32_bf16 layout (verified rounds 1-22):
//   A: row m = lane&15, k = (lane>>4)*8 + i
//   B: col n = lane&15, k = (lane>>4)*8 + i
//   C/D: col n = lane&15, row m = (lane>>4)*4 + r
//   o'(16t+m) = 32*(t>>1) + 8*(m>>2) + 4*(t&1) + (m&3)

namespace {

constexpr int kF = 256;
constexpr int kH = 64;
constexpr int kB = 8192;

constexpr int kFPB     = 4;               // features per block (one per wave)
constexpr int kRPC     = 128;             // rows per chunk
constexpr int kChunks  = 4;               // chunks per block
constexpr int kRPBlk   = kRPC * kChunks;  // 512 rows per block
constexpr int kThreads = 256;             // 4 waves
constexpr int kFG      = kF / kFPB;       // 64 feature groups
constexpr int kSlabs   = kB / kRPBlk;     // 16 row slabs
constexpr int kBlocks  = kFG * kSlabs;    // 1024 = 4 blocks/CU persistent
constexpr int kXP      = 12;              // pass-dim stride

using f32x4  = __attribute__((ext_vector_type(4))) float;
using bf16x4 = __attribute__((ext_vector_type(4))) __bf16;
using bf16x8 = __attribute__((ext_vector_type(8))) __bf16;

// ---- prep: pack w2 (o'-out-permuted, bf16, fragment-major), b2
// (o'-permuted, C-order), w3 (bf16). Verified v10-v22. ----
__global__ __launch_bounds__(256)
void pack_params(const float* __restrict__ w2, const float* __restrict__ b2,
                 const float* __restrict__ w3, __bf16* __restrict__ w2p,
                 float* __restrict__ b2p, __bf16* __restrict__ w3p)
{
  const int wid  = (int)threadIdx.x >> 6;
  const int lane = (int)threadIdx.x & 63;
  const int f    = (int)blockIdx.x * 4 + wid;
  const int l15  = lane & 15;
  const int lg   = lane >> 4;

  const float* w2f = w2 + (size_t)f * (kH * kH);
  #pragma unroll
  for (int t = 0; t < 4; ++t) {
    const int o2 = 32 * (t >> 1) + 8 * (l15 >> 2) + 4 * (t & 1) + (l15 & 3);
    #pragma unroll
    for (int ks = 0; ks < 2; ++ks) {
      const float* p = w2f + o2 * kH + ks * 32 + lg * 8;
      const f32x4 lo = *reinterpret_cast<const f32x4*>(p);
      const f32x4 hi = *reinterpret_cast<const f32x4*>(p + 4);
      const bf16x8 v = __builtin_shufflevector(
          __builtin_convertvector(lo, bf16x4),
          __builtin_convertvector(hi, bf16x4), 0, 1, 2, 3, 4, 5, 6, 7);
      *reinterpret_cast<bf16x8*>(
          w2p + (((size_t)f * 8 + t * 2 + ks) * 64 + lane) * 8) = v;
    }
  }

  {
    const int jt = lane >> 4, jlg = (lane >> 2) & 3, jr = lane & 3;
    const int o  = 32 * (jt >> 1) + 8 * jlg + 4 * (jt & 1) + jr;
    b2p[(size_t)f * kH + lane] = b2[(size_t)f * kH + o];
  }
  w3p[(size_t)f * kH + lane] = (__bf16)w3[(size_t)f * kH + lane];
}

__global__ __launch_bounds__(kThreads, 3)
void mlp_pf_v23(const float* __restrict__ x,
                const float* __restrict__ w1,
                const float* __restrict__ b1,
                const __bf16* __restrict__ w2p,
                const float* __restrict__ b2p,
                const __bf16* __restrict__ w3p,
                const float* __restrict__ b3,
                float* __restrict__ out)
{
  __shared__ float xs[kFPB][16][kXP];     // 3 KB [feat][l15][pass]
  __shared__ float outb[kRPC][kFPB + 1];  // 2.56 KB (pad: conflict-free)

  const int tid  = (int)threadIdx.x;
  const int wid  = tid >> 6;
  const int lane = tid & 63;
  const int l15  = lane & 15;
  const int lg   = lane >> 4;

  const int fg   = (int)blockIdx.x >> 4;       // 0..63
  const int slab = (int)blockIdx.x & 15;       // 0..15; XCD = slab%8
  const int f    = fg * kFPB + wid;            // this wave's feature
  const int rs0  = slab * kRPBlk;              // slab row base

  // ================= PROLOGUE (paid once per 512 rows) =================
  bf16x8 w2frag[4][2];
  {
    const __bf16* base = w2p + ((size_t)f * 8 * 64 + lane) * 8;
    #pragma unroll
    for (int t = 0; t < 4; ++t)
      #pragma unroll
      for (int ks = 0; ks < 2; ++ks)
        w2frag[t][ks] = *reinterpret_cast<const bf16x8*>(
            base + (size_t)(t * 2 + ks) * 64 * 8);
  }

  f32x4 w1v[2][2], b1v[2][2];
  #pragma unroll
  for (int ks = 0; ks < 2; ++ks) {
    const float* pw = w1 + f * kH + ks * 32 + lg * 8;
    const float* pb = b1 + f * kH + ks * 32 + lg * 8;
    w1v[ks][0] = *reinterpret_cast<const f32x4*>(pw);
    w1v[ks][1] = *reinterpret_cast<const f32x4*>(pw + 4);
    b1v[ks][0] = *reinterpret_cast<const f32x4*>(pb);
    b1v[ks][1] = *reinterpret_cast<const f32x4*>(pb + 4);
  }
  f32x4 b2c[4];
  #pragma unroll
  for (int t = 0; t < 4; ++t)
    b2c[t] = *reinterpret_cast<const f32x4*>(b2p + f * kH + t * 16 + lg * 4);
  bf16x8 w3f[2];
  #pragma unroll
  for (int ks = 0; ks < 2; ++ks)
    w3f[ks] = *reinterpret_cast<const bf16x8*>(w3p + f * kH + ks * 32 + lg * 8);
  const float b3v = b3[f];
  const f32x4 b3c = {b3v, b3v, b3v, b3v};

  const f32x4 zero4 = {0.f, 0.f, 0.f, 0.f};
  float keep = 0.f;

  struct PairH1 { bf16x8 a0, a1, b0, b1; };

  auto mk = [&](float xa, float xb) -> PairH1 {
    PairH1 r;
    #pragma unroll
    for (int ks = 0; ks < 2; ++ks) {
      f32x4 aA = w1v[ks][0] * xa + b1v[ks][0];
      f32x4 bA = w1v[ks][1] * xa + b1v[ks][1];
      f32x4 aB = w1v[ks][0] * xb + b1v[ks][0];
      f32x4 bB = w1v[ks][1] * xb + b1v[ks][1];
      aA = __builtin_elementwise_max(aA, zero4);
      bA = __builtin_elementwise_max(bA, zero4);
      aB = __builtin_elementwise_max(aB, zero4);
      bB = __builtin_elementwise_max(bB, zero4);
      const bf16x8 hA = __builtin_shufflevector(
          __builtin_convertvector(aA, bf16x4),
          __builtin_convertvector(bA, bf16x4), 0, 1, 2, 3, 4, 5, 6, 7);
      const bf16x8 hB = __builtin_shufflevector(
          __builtin_convertvector(aB, bf16x4),
          __builtin_convertvector(bB, bf16x4), 0, 1, 2, 3, 4, 5, 6, 7);
      if (ks == 0) { r.a0 = hA; r.b0 = hB; } else { r.a1 = hA; r.b1 = hB; }
    }
    return r;
  };

  auto pack2 = [&](const f32x4& a, const f32x4& b) -> bf16x8 {
    return __builtin_shufflevector(
        __builtin_convertvector(__builtin_elementwise_max(a, zero4), bf16x4),
        __builtin_convertvector(__builtin_elementwise_max(b, zero4), bf16x4),
        0, 1, 2, 3, 4, 5, 6, 7);
  };

  auto fin = [&](const PairH1& h, int PI) {
    f32x4 accA[4], accB[4];
    #pragma unroll
    for (int t = 0; t < 4; ++t) {
      accA[t] = __builtin_amdgcn_mfma_f32_16x16x32_bf16(
          w2frag[t][0], h.a0, b2c[t], 0, 0, 0);
      accB[t] = __builtin_amdgcn_mfma_f32_16x16x32_bf16(
          w2frag[t][0], h.b0, b2c[t], 0, 0, 0);
      accA[t] = __builtin_amdgcn_mfma_f32_16x16x32_bf16(
          w2frag[t][1], h.a1, accA[t], 0, 0, 0);
      accB[t] = __builtin_amdgcn_mfma_f32_16x16x32_bf16(
          w2frag[t][1], h.b1, accB[t], 0, 0, 0);
    }
    const bf16x8 h2A0 = pack2(accA[0], accA[1]);
    const bf16x8 h2A1 = pack2(accA[2], accA[3]);
    const bf16x8 h2B0 = pack2(accB[0], accB[1]);
    const bf16x8 h2B1 = pack2(accB[2], accB[3]);

    f32x4 dA = __builtin_amdgcn_mfma_f32_16x16x32_bf16(w3f[0], h2A0, b3c, 0, 0, 0);
    f32x4 dB = __builtin_amdgcn_mfma_f32_16x16x32_bf16(w3f[0], h2B0, b3c, 0, 0, 0);
    dA = __builtin_amdgcn_mfma_f32_16x16x32_bf16(w3f[1], h2A1, dA, 0, 0, 0);
    dB = __builtin_amdgcn_mfma_f32_16x16x32_bf16(w3f[1], h2B1, dB, 0, 0, 0);

    const int pA = 2 * PI, pB = 2 * PI + 1;
    keep = (lg == (pA & 3)) ? dA[0] : keep;
    keep = (lg == (pB & 3)) ? dB[0] : keep;
    if ((pB & 3) == 3) {
      outb[(pB >> 2) * 64 + lane][wid] = keep;   // b3 folded in
    }
  };

  // ================= 4 chunks of the verified body =================
  #pragma unroll 1
  for (int ck = 0; ck < kChunks; ++ck) {
    const int r0 = rs0 + ck * kRPC;

    if (tid < kRPC) {
      const int rr = tid;
      const f32x4 v = *reinterpret_cast<const f32x4*>(
          x + (size_t)(r0 + rr) * kF + fg * kFPB);
      const int a = rr & 15, b = rr >> 4;
      xs[0][a][b] = v[0]; xs[1][a][b] = v[1];
      xs[2][a][b] = v[2]; xs[3][a][b] = v[3];
    }
    __syncthreads();   // xs ready

    const f32x4 xq0 = *reinterpret_cast<const f32x4*>(&xs[wid][l15][0]);
    const f32x4 xq1 = *reinterpret_cast<const f32x4*>(&xs[wid][l15][4]);

    PairH1 c  = mk(xq0[0], xq0[1]);
    PairH1 n1 = mk(xq0[2], xq0[3]);
    fin(c, 0);
    PairH1 n2 = mk(xq1[0], xq1[1]);
    fin(n1, 1);
    PairH1 n3 = mk(xq1[2], xq1[3]);
    fin(n2, 2);
    fin(n3, 3);

    __syncthreads();   // outb ready

    if (tid < kRPC) {
      const int rr = tid;
      const f32x4 v = {outb[rr][0], outb[rr][1], outb[rr][2], outb[rr][3]};
      *reinterpret_cast<f32x4*>(out + (size_t)(r0 + rr) * kF + fg * kFPB) = v;
    }
    __syncthreads();   // protect xs/outb for next chunk
  }
}

}  // namespace

extern "C" void kernel_launch(void* const* d_in, const int* in_sizes, int n_in,
                              void* d_out, int out_size, void* d_ws, size_t ws_size,
                              hipStream_t stream) {
  const float* x  = (const float*)d_in[0];
  const float* w1 = (const float*)d_in[1];
  const float* b1 = (const float*)d_in[2];
  const float* w2 = (const float*)d_in[3];
  const float* b2 = (const float*)d_in[4];
  const float* w3 = (const float*)d_in[5];
  const float* b3 = (const float*)d_in[6];
  float* out = (float*)d_out;

  __bf16* w2p = (__bf16*)d_ws;                           // 2 MB
  float*  b2p = (float*)((char*)d_ws + (2u << 20));      // 64 KB
  __bf16* w3p = (__bf16*)((char*)d_ws + (2u << 20) + (64u << 10));  // 32 KB

  hipLaunchKernelGGL(pack_params, dim3(kF / 4), dim3(256), 0, stream,
                     w2, b2, w3, w2p, b2p, w3p);
  hipLaunchKernelGGL(mlp_pf_v23, dim3(kBlocks), dim3(kThreads), 0, stream,
                     x, w1, b1, w2p, b2p, w3p, b3, out);
}